// Round 2
// 555.000 us; speedup vs baseline: 1.2535x; 1.2535x over previous
//
#include <hip/hip_runtime.h>
#include <hip/hip_bf16.h>

typedef unsigned short u16;
typedef unsigned char u8;
typedef __attribute__((ext_vector_type(8))) short bf16x8;
typedef __attribute__((ext_vector_type(4))) float f32x4;

#define BB 2
#define LL 4096
#define GG 256
#define HH 12
#define DD 64
#define NB 32
#define WW 255
#define VV 32
#define NCHUNK 17
#define LKEY 640      // 384 local-window keys + 256 global keys
#define GKEY 4352     // 256 global keys + 4096 long keys

// ---------- bf16 helpers ----------
__device__ __forceinline__ float bf2f(u16 u) {
  return __uint_as_float(((unsigned)u) << 16);
}
__device__ __forceinline__ u16 f2bf(float f) {
  unsigned u = __float_as_uint(f);
  u += 0x7FFFu + ((u >> 16) & 1u);
  return (u16)(u >> 16);
}
__device__ __forceinline__ float4 ld4bf(const u16* p) {
  ushort4 q = *reinterpret_cast<const ushort4*>(p);
  return make_float4(bf2f(q.x), bf2f(q.y), bf2f(q.z), bf2f(q.w));
}
__device__ __forceinline__ float ldx1(const void* p, size_t idx, bool f32m) {
  if (f32m) return reinterpret_cast<const float*>(p)[idx];
  return bf2f(reinterpret_cast<const u16*>(p)[idx]);
}

// ---------- dtype detector (bf16 N(0,1) never has exponent >= 134) ----------
__global__ void detect_dtype(const void* __restrict__ x, int* __restrict__ flag) {
  __shared__ int cnt;
  if (threadIdx.x == 0) cnt = 0;
  __syncthreads();
  const u16* p = reinterpret_cast<const u16*>(x);
  int c = 0;
  for (int i = threadIdx.x; i < 4096; i += 256) {
    int e = (p[i] >> 7) & 0xFF;
    if (e >= 134) c++;
  }
  atomicAdd(&cnt, c);
  __syncthreads();
  if (threadIdx.x == 0) *flag = (cnt >= 64) ? 1 : 0;
}

// ---------- pack mask+id into one byte per (q,key), blocked layout ----------
// byte = (id & 31) | (!mask << 7); invalid window positions -> 0x80.
__global__ __launch_bounds__(256)
void pack_l(const int* __restrict__ m_l2l, const int* __restrict__ m_l2g,
            const int* __restrict__ i_l2l, const int* __restrict__ i_l2g,
            u8* __restrict__ pk) {
  const unsigned idx = blockIdx.x * 256u + threadIdx.x;   // < BB*LL*LKEY
  const unsigned c = idx % (unsigned)LKEY;
  const unsigned bt = idx / (unsigned)LKEY;               // b*LL + t
  const int t = bt & (LL - 1);
  int mask = 0, id = 0;
  if (c < 384u) {
    const int rr = (int)c - (t & 127) - 1;
    const int jabs = (((t >> 7) - 1) << 7) + (int)c;
    if (rr >= 0 && rr < WW && jabs >= 0 && jabs < LL) {
      const size_t base = (size_t)bt * WW + rr;
      mask = m_l2l[base]; id = i_l2l[base];
    }
  } else {
    const size_t base = (size_t)bt * GG + (c - 384u);
    mask = m_l2g[base]; id = i_l2g[base];
  }
  pk[idx] = (u8)((id & 31) | ((mask ^ 1) << 7));
}

__global__ __launch_bounds__(256)
void pack_g(const int* __restrict__ m_g2g, const int* __restrict__ m_g2l,
            const int* __restrict__ i_g2g, const int* __restrict__ i_g2l,
            u8* __restrict__ pk) {
  const unsigned idx = blockIdx.x * 256u + threadIdx.x;   // < BB*GG*GKEY
  const unsigned c = idx % (unsigned)GKEY;
  const unsigned bq = idx / (unsigned)GKEY;               // b*GG + q
  int mask, id;
  if (c < 256u) {
    const size_t base = (size_t)bq * GG + c;
    mask = m_g2g[base]; id = i_g2g[base];
  } else {
    const size_t base = (size_t)bq * (size_t)LL + (c - 256u);
    mask = m_g2l[base]; id = i_g2l[base];
  }
  pk[idx] = (u8)((id & 31) | ((mask ^ 1) << 7));
}

// ---------- fused QKV GEMM: 3 weights, one A ----------
// Q output is pre-scaled by 0.125 (= 1/sqrt(D)); power-of-2 => bit-exact fold
// of the softmax scale into both Q.K and Q.rel_emb paths.
__global__ __launch_bounds__(256)
void gemm_qkv(const void* __restrict__ A,
              const void* __restrict__ W0, const void* __restrict__ W1, const void* __restrict__ W2,
              const void* __restrict__ b0, const void* __restrict__ b1, const void* __restrict__ b2,
              u16* __restrict__ C0, u16* __restrict__ C1, u16* __restrict__ C2,
              int M, const int* __restrict__ flagp) {
  __shared__ u16 As[128][72];
  __shared__ u16 Bs[64][74];
  const bool f32m = (*flagp != 0);
  const int K = 768, Nn = 768;
  const int which = blockIdx.x / 12;
  const int col0 = (blockIdx.x % 12) << 6;
  const int row0 = blockIdx.y << 7;
  const void* Wm = (which == 0) ? W0 : ((which == 1) ? W1 : W2);
  const void* bias = (which == 0) ? b0 : ((which == 1) ? b1 : b2);
  u16* Cv = (which == 0) ? C0 : ((which == 1) ? C1 : C2);
  const float sc = (which == 0) ? 0.125f : 1.0f;

  const int tid = threadIdx.x;
  const int lane = tid & 63, wv = tid >> 6;
  const int lm = lane & 15, quad = lane >> 4;
  const int mb = wv << 5;

  f32x4 acc[2][4];
  #pragma unroll
  for (int mt = 0; mt < 2; mt++)
    #pragma unroll
    for (int nt = 0; nt < 4; nt++) acc[mt][nt] = (f32x4){0.f, 0.f, 0.f, 0.f};

  for (int k0 = 0; k0 < K; k0 += 64) {
    __syncthreads();
    {
      const int row = tid >> 1, kg = (tid & 1) << 5;
      const size_t aidx = (size_t)(row0 + row) * K + k0 + kg;
      if (f32m) {
        const float* ap = reinterpret_cast<const float*>(A) + aidx;
        #pragma unroll
        for (int c = 0; c < 8; c++) {
          float4 v = *reinterpret_cast<const float4*>(ap + (c << 2));
          As[row][kg + (c << 2) + 0] = f2bf(v.x);
          As[row][kg + (c << 2) + 1] = f2bf(v.y);
          As[row][kg + (c << 2) + 2] = f2bf(v.z);
          As[row][kg + (c << 2) + 3] = f2bf(v.w);
        }
      } else {
        const int4* ap = reinterpret_cast<const int4*>(reinterpret_cast<const u16*>(A) + aidx);
        #pragma unroll
        for (int c = 0; c < 4; c++)
          *reinterpret_cast<int4*>(&As[row][kg + (c << 3)]) = ap[c];
      }
    }
    #pragma unroll
    for (int p = 0; p < 2; p++) {
      const int idx = tid + (p << 8);
      const int kr = idx >> 3, ng = (idx & 7) << 3;
      const size_t widx = (size_t)(k0 + kr) * Nn + col0 + ng;
      u16 wv8[8];
      if (f32m) {
        const float* wp = reinterpret_cast<const float*>(Wm) + widx;
        float4 a = *reinterpret_cast<const float4*>(wp);
        float4 bq = *reinterpret_cast<const float4*>(wp + 4);
        wv8[0] = f2bf(a.x); wv8[1] = f2bf(a.y); wv8[2] = f2bf(a.z); wv8[3] = f2bf(a.w);
        wv8[4] = f2bf(bq.x); wv8[5] = f2bf(bq.y); wv8[6] = f2bf(bq.z); wv8[7] = f2bf(bq.w);
      } else {
        int4 raw = *reinterpret_cast<const int4*>(reinterpret_cast<const u16*>(Wm) + widx);
        *reinterpret_cast<int4*>(wv8) = raw;
      }
      #pragma unroll
      for (int j = 0; j < 8; j++) Bs[ng + j][kr] = wv8[j];
    }
    __syncthreads();

    #pragma unroll
    for (int kk = 0; kk < 2; kk++) {
      bf16x8 af[2], bfr[4];
      #pragma unroll
      for (int mt = 0; mt < 2; mt++)
        af[mt] = *reinterpret_cast<const bf16x8*>(&As[mb + (mt << 4) + lm][(kk << 5) + (quad << 3)]);
      #pragma unroll
      for (int nt = 0; nt < 4; nt++)
        bfr[nt] = *reinterpret_cast<const bf16x8*>(&Bs[(nt << 4) + lm][(kk << 5) + (quad << 3)]);
      #pragma unroll
      for (int mt = 0; mt < 2; mt++)
        #pragma unroll
        for (int nt = 0; nt < 4; nt++)
          acc[mt][nt] = __builtin_amdgcn_mfma_f32_16x16x32_bf16(af[mt], bfr[nt], acc[mt][nt], 0, 0, 0);
    }
  }

  #pragma unroll
  for (int nt = 0; nt < 4; nt++) {
    const int gcol = col0 + (nt << 4) + lm;
    const float bv = ldx1(bias, gcol, f32m);
    #pragma unroll
    for (int mt = 0; mt < 2; mt++)
      #pragma unroll
      for (int r = 0; r < 4; r++) {
        const int grow = row0 + mb + (mt << 4) + (quad << 2) + r;
        Cv[(size_t)grow * Nn + gcol] = f2bf((acc[mt][nt][r] + bv) * sc);
      }
  }
}

// ---------- output-projection GEMM (A internal bf16, out external dual) ----------
__global__ __launch_bounds__(256)
void gemm_out(const u16* __restrict__ A, const void* __restrict__ Wm,
              const void* __restrict__ bias, void* __restrict__ Cv,
              size_t c_off, int M, const int* __restrict__ flagp) {
  __shared__ u16 As[128][72];
  __shared__ u16 Bs[64][74];
  const bool f32m = (*flagp != 0);
  const int K = 768, Nn = 768;
  const int tid = threadIdx.x;
  const int row0 = blockIdx.y << 7, col0 = blockIdx.x << 6;
  const int lane = tid & 63, wv = tid >> 6;
  const int lm = lane & 15, quad = lane >> 4;
  const int mb = wv << 5;

  f32x4 acc[2][4];
  #pragma unroll
  for (int mt = 0; mt < 2; mt++)
    #pragma unroll
    for (int nt = 0; nt < 4; nt++) acc[mt][nt] = (f32x4){0.f, 0.f, 0.f, 0.f};

  for (int k0 = 0; k0 < K; k0 += 64) {
    __syncthreads();
    {
      const int row = tid >> 1, kg = (tid & 1) << 5;
      const int4* ap = reinterpret_cast<const int4*>(A + (size_t)(row0 + row) * K + k0 + kg);
      #pragma unroll
      for (int c = 0; c < 4; c++)
        *reinterpret_cast<int4*>(&As[row][kg + (c << 3)]) = ap[c];
    }
    #pragma unroll
    for (int p = 0; p < 2; p++) {
      const int idx = tid + (p << 8);
      const int kr = idx >> 3, ng = (idx & 7) << 3;
      const size_t widx = (size_t)(k0 + kr) * Nn + col0 + ng;
      u16 wv8[8];
      if (f32m) {
        const float* wp = reinterpret_cast<const float*>(Wm) + widx;
        float4 a = *reinterpret_cast<const float4*>(wp);
        float4 bq = *reinterpret_cast<const float4*>(wp + 4);
        wv8[0] = f2bf(a.x); wv8[1] = f2bf(a.y); wv8[2] = f2bf(a.z); wv8[3] = f2bf(a.w);
        wv8[4] = f2bf(bq.x); wv8[5] = f2bf(bq.y); wv8[6] = f2bf(bq.z); wv8[7] = f2bf(bq.w);
      } else {
        int4 raw = *reinterpret_cast<const int4*>(reinterpret_cast<const u16*>(Wm) + widx);
        *reinterpret_cast<int4*>(wv8) = raw;
      }
      #pragma unroll
      for (int j = 0; j < 8; j++) Bs[ng + j][kr] = wv8[j];
    }
    __syncthreads();

    #pragma unroll
    for (int kk = 0; kk < 2; kk++) {
      bf16x8 af[2], bfr[4];
      #pragma unroll
      for (int mt = 0; mt < 2; mt++)
        af[mt] = *reinterpret_cast<const bf16x8*>(&As[mb + (mt << 4) + lm][(kk << 5) + (quad << 3)]);
      #pragma unroll
      for (int nt = 0; nt < 4; nt++)
        bfr[nt] = *reinterpret_cast<const bf16x8*>(&Bs[(nt << 4) + lm][(kk << 5) + (quad << 3)]);
      #pragma unroll
      for (int mt = 0; mt < 2; mt++)
        #pragma unroll
        for (int nt = 0; nt < 4; nt++)
          acc[mt][nt] = __builtin_amdgcn_mfma_f32_16x16x32_bf16(af[mt], bfr[nt], acc[mt][nt], 0, 0, 0);
    }
  }

  #pragma unroll
  for (int nt = 0; nt < 4; nt++) {
    const int gcol = col0 + (nt << 4) + lm;
    const float bv = ldx1(bias, gcol, f32m);
    #pragma unroll
    for (int mt = 0; mt < 2; mt++)
      #pragma unroll
      for (int r = 0; r < 4; r++) {
        const int grow = row0 + mb + (mt << 4) + (quad << 2) + r;
        const float v = acc[mt][nt][r] + bv;
        if (f32m)
          reinterpret_cast<float*>(Cv)[c_off + (size_t)grow * Nn + gcol] = v;
        else
          reinterpret_cast<u16*>(Cv)[c_off + (size_t)grow * Nn + gcol] = f2bf(v);
      }
  }
}

// ---------- rel_all[b,t,h,r] = q.emb + bias*0.125 (q pre-scaled) ----------
__global__ __launch_bounds__(256)
void relk(const u16* __restrict__ Q, const void* __restrict__ emb,
          const void* __restrict__ bias, u16* __restrict__ outp, int T,
          const int* __restrict__ flagp) {
  const bool f32m = (*flagp != 0);
  const int h = blockIdx.y, b = blockIdx.z;
  const int t0 = blockIdx.x << 6;
  const int tid = threadIdx.x;
  __shared__ float Qst[64][68];
  __shared__ float Es[64][36];
  #pragma unroll
  for (int i = 0; i < 4; i++) {
    const int idx = tid + (i << 8);
    const int tt = idx >> 4, d = (idx & 15) << 2;
    float4 v = ld4bf(Q + (((size_t)b * T + t0 + tt) * HH + h) * DD + d);
    Qst[d + 0][tt] = v.x; Qst[d + 1][tt] = v.y;
    Qst[d + 2][tt] = v.z; Qst[d + 3][tt] = v.w;
  }
  #pragma unroll
  for (int i = 0; i < 8; i++) {
    const int idx = tid + (i << 8);
    const int r = idx >> 6, d = idx & 63;
    Es[d][r] = ldx1(emb, ((size_t)r * HH + h) * DD + d, f32m);
  }
  __syncthreads();
  const int tq = (tid & 31) << 1;
  const int r0 = (tid >> 5) << 2;
  float acc[2][4] = {};
  #pragma unroll 8
  for (int d = 0; d < 64; d++) {
    float2 qq = *reinterpret_cast<const float2*>(&Qst[d][tq]);
    float4 e = *reinterpret_cast<const float4*>(&Es[d][r0]);
    acc[0][0] += qq.x * e.x; acc[0][1] += qq.x * e.y;
    acc[0][2] += qq.x * e.z; acc[0][3] += qq.x * e.w;
    acc[1][0] += qq.y * e.x; acc[1][1] += qq.y * e.y;
    acc[1][2] += qq.y * e.z; acc[1][3] += qq.y * e.w;
  }
  float bv[4];
  #pragma unroll
  for (int j = 0; j < 4; j++) bv[j] = ldx1(bias, (size_t)(r0 + j) * HH + h, f32m) * 0.125f;
  #pragma unroll
  for (int i = 0; i < 2; i++) {
    ushort4 o;
    o.x = f2bf(acc[i][0] + bv[0]); o.y = f2bf(acc[i][1] + bv[1]);
    o.z = f2bf(acc[i][2] + bv[2]); o.w = f2bf(acc[i][3] + bv[3]);
    *reinterpret_cast<ushort4*>(&outp[(((size_t)b * T + t0 + tq + i) * HH + h) * VV + r0]) = o;
  }
}

// ---------- long-token attention: merged 128-query block, 512 threads ----------
// grid (12, 32, 2) with in-kernel XCD swizzle: the 12 head-blocks sharing
// the packed mask/id rows get linear ids congruent mod 8 -> same XCD L2.
__global__ __launch_bounds__(512)
void lattn(const u16* __restrict__ lq, const u16* __restrict__ lk, const u16* __restrict__ lv,
           const u16* __restrict__ gk, const u16* __restrict__ gv,
           const u8* __restrict__ pkl, const u16* __restrict__ rel,
           u16* __restrict__ lctx) {
  const int fid = blockIdx.x + 12 * (blockIdx.y + (blockIdx.z << 5));
  const int hg = fid >> 3;                       // 0..95
  const int h = hg % 12;
  const int fl = (fid & 7) + ((hg / 12) << 3);   // 0..63 = b*32+n
  const int n = fl & 31, b = fl >> 5;
  const int tid = threadIdx.x;
  __shared__ u16 Kt[64][72];    // [k][d]
  __shared__ u16 Vt[64][74];    // [d][k] transposed
  __shared__ u16 Pt[128][74];   // [q][k] (wave-private rows)
  __shared__ u16 Rl[128][36];   // per-q rel row (32 bf16, pre-scaled)

  const int lane = tid & 63, wv = tid >> 6;      // wv 0..7
  const int ln = lane & 15, quad = lane >> 4;
  const int tbase = n << 7;

  // wave-local rel-row staging (each wave stages its own 16 rows)
  {
    const int qr = (wv << 4) + (lane >> 2);
    const int seg = (lane & 3) << 3;
    *reinterpret_cast<int4*>(&Rl[qr][seg]) = *reinterpret_cast<const int4*>(
        rel + (((size_t)b * LL + tbase + qr) * HH + h) * VV + seg);
  }

  bf16x8 aq[2];
  {
    const int t = tbase + (wv << 4) + ln;
    const u16* qp = lq + (((size_t)b * LL + t) * HH + h) * DD + (quad << 3);
    aq[0] = *reinterpret_cast<const bf16x8*>(qp);
    aq[1] = *reinterpret_cast<const bf16x8*>(qp + 32);
  }

  const u8* pkb = pkl + ((size_t)b * LL + tbase) * LKEY;
  const int skey = tid >> 3, sdg = (tid & 7) << 3;   // staging identity (1 pass)

  f32x4 Oacc[4];
  #pragma unroll
  for (int dt = 0; dt < 4; dt++) Oacc[dt] = (f32x4){0.f, 0.f, 0.f, 0.f};
  float lpart[4] = {};

  for (int tile = 0; tile < 10; tile++) {
    const int c0 = tile << 6;
    const bool isg = (tile >= 6);   // uniform per tile: local window vs global keys

    // packed additive bias: 1 ubyte load + LDS gather + cndmask per element
    float badd[16];
    #pragma unroll
    for (int r = 0; r < 4; r++) {
      const int qrow = (wv << 4) + (quad << 2) + r;
      const u8* prow = pkb + qrow * LKEY + c0 + ln;
      #pragma unroll
      for (int kt = 0; kt < 4; kt++) {
        const u8 pb = prow[kt << 4];
        const float rv = bf2f(Rl[qrow][pb & 31]);
        badd[(kt << 2) + r] = (pb & 0x80) ? (rv - 10000.f) : rv;
      }
    }

    __syncthreads();
    {
      int4 kraw = {0, 0, 0, 0}, vraw = {0, 0, 0, 0};
      if (isg) {
        const size_t base = (((size_t)b * GG + (c0 - 384) + skey) * HH + h) * DD + sdg;
        kraw = *reinterpret_cast<const int4*>(gk + base);
        vraw = *reinterpret_cast<const int4*>(gv + base);
      } else {
        const int jabs = ((n - 1) << 7) + c0 + skey;
        if (jabs >= 0 && jabs < LL) {
          const size_t base = (((size_t)b * LL + jabs) * HH + h) * DD + sdg;
          kraw = *reinterpret_cast<const int4*>(lk + base);
          vraw = *reinterpret_cast<const int4*>(lv + base);
        }
      }
      *reinterpret_cast<int4*>(&Kt[skey][sdg]) = kraw;
      u16 vb[8];
      *reinterpret_cast<int4*>(vb) = vraw;
      #pragma unroll
      for (int j = 0; j < 8; j++) Vt[sdg + j][skey] = vb[j];
    }
    __syncthreads();

    f32x4 Sacc[4];
    #pragma unroll
    for (int kt = 0; kt < 4; kt++) Sacc[kt] = (f32x4){0.f, 0.f, 0.f, 0.f};
    __builtin_amdgcn_s_setprio(1);
    #pragma unroll
    for (int kk = 0; kk < 2; kk++) {
      bf16x8 bk[4];
      #pragma unroll
      for (int kt = 0; kt < 4; kt++)
        bk[kt] = *reinterpret_cast<const bf16x8*>(&Kt[(kt << 4) + ln][(kk << 5) + (quad << 3)]);
      #pragma unroll
      for (int kt = 0; kt < 4; kt++)
        Sacc[kt] = __builtin_amdgcn_mfma_f32_16x16x32_bf16(aq[kk], bk[kt], Sacc[kt], 0, 0, 0);
    }
    __builtin_amdgcn_s_setprio(0);

    #pragma unroll
    for (int kt = 0; kt < 4; kt++)
      #pragma unroll
      for (int r = 0; r < 4; r++) {
        const int ql = (wv << 4) + (quad << 2) + r;
        float s = fminf(fmaxf(Sacc[kt][r], -60.f), 60.f) + badd[(kt << 2) + r];
        const u16 p16 = f2bf(__expf(s));
        Pt[ql][(kt << 4) + ln] = p16;
        lpart[r] += bf2f(p16);
      }

    __builtin_amdgcn_s_setprio(1);
    #pragma unroll
    for (int kk = 0; kk < 2; kk++) {
      bf16x8 ap = *reinterpret_cast<const bf16x8*>(&Pt[(wv << 4) + ln][(kk << 5) + (quad << 3)]);
      #pragma unroll
      for (int dt = 0; dt < 4; dt++) {
        bf16x8 bv = *reinterpret_cast<const bf16x8*>(&Vt[(dt << 4) + ln][(kk << 5) + (quad << 3)]);
        Oacc[dt] = __builtin_amdgcn_mfma_f32_16x16x32_bf16(ap, bv, Oacc[dt], 0, 0, 0);
      }
    }
    __builtin_amdgcn_s_setprio(0);
  }

  #pragma unroll
  for (int r = 0; r < 4; r++) {
    float v = lpart[r];
    v += __shfl_xor(v, 1); v += __shfl_xor(v, 2);
    v += __shfl_xor(v, 4); v += __shfl_xor(v, 8);
    const float inv = 1.0f / v;
    const int t = tbase + (wv << 4) + (quad << 2) + r;
    const size_t base = (((size_t)b * LL + t) * HH + h) * DD;
    #pragma unroll
    for (int dt = 0; dt < 4; dt++)
      lctx[base + (dt << 4) + ln] = f2bf(Oacc[dt][r] * inv);
  }
}

// ---------- global-token attention (17 chunks x 256 keys, XCD-swizzled) ----------
__global__ __launch_bounds__(256)
void gattn(const u16* __restrict__ gq, const u16* __restrict__ gk, const u16* __restrict__ gv,
           const u16* __restrict__ lk, const u16* __restrict__ lv,
           const u8* __restrict__ pkg, const u16* __restrict__ relg,
           float* __restrict__ po, float* __restrict__ pl) {
  const int fid = blockIdx.x + 12 * (blockIdx.y + 17 * blockIdx.z);
  const int hg = fid >> 3;
  const int h = hg % 12;
  const int fl = (fid & 7) + ((hg / 12) << 3);   // 0..135
  const int chunk = fl % 17;
  const int bqt = fl / 17;
  const int b = bqt >> 2, qt = bqt & 3;
  const int tid = threadIdx.x;
  __shared__ u16 Kt[64][72];
  __shared__ u16 Vt[64][74];
  __shared__ u16 Pt[64][74];
  __shared__ u16 Rg[64][36];

  const int lane = tid & 63, wv = tid >> 6;
  const int ln = lane & 15, quad = lane >> 4;
  const int kbase = chunk << 8;
  const bool isgg = (chunk == 0);   // uniform: chunk 0 = g2g keys, else long keys

  {
    const int qr = (wv << 4) + (lane >> 2);
    const int seg = (lane & 3) << 3;
    *reinterpret_cast<int4*>(&Rg[qr][seg]) = *reinterpret_cast<const int4*>(
        relg + (((size_t)b * GG + (qt << 6) + qr) * HH + h) * VV + seg);
  }

  bf16x8 aq[2];
  {
    const int qa = (qt << 6) + (wv << 4) + ln;
    const u16* qp = gq + (((size_t)b * GG + qa) * HH + h) * DD + (quad << 3);
    aq[0] = *reinterpret_cast<const bf16x8*>(qp);
    aq[1] = *reinterpret_cast<const bf16x8*>(qp + 32);
  }

  const u8* pkb = pkg + ((size_t)b * GG + (qt << 6)) * GKEY;

  f32x4 Oacc[4];
  #pragma unroll
  for (int dt = 0; dt < 4; dt++) Oacc[dt] = (f32x4){0.f, 0.f, 0.f, 0.f};
  float lpart[4] = {};

  for (int tile = 0; tile < 4; tile++) {
    const int c0 = kbase + (tile << 6);

    float badd[16];
    #pragma unroll
    for (int r = 0; r < 4; r++) {
      const int qrow = (wv << 4) + (quad << 2) + r;
      const u8* prow = pkb + qrow * GKEY + c0 + ln;
      #pragma unroll
      for (int kt = 0; kt < 4; kt++) {
        const u8 pb = prow[kt << 4];
        const float rv = bf2f(Rg[qrow][pb & 31]);
        badd[(kt << 2) + r] = (pb & 0x80) ? (rv - 10000.f) : rv;
      }
    }

    __syncthreads();
    #pragma unroll
    for (int p = 0; p < 2; p++) {
      const int idx = tid + (p << 8);
      const int key = idx >> 3, dg = (idx & 7) << 3;
      const int kc = c0 + key;
      int4 kraw, vraw;
      if (isgg) {
        const size_t base = (((size_t)b * GG + kc) * HH + h) * DD + dg;
        kraw = *reinterpret_cast<const int4*>(gk + base);
        vraw = *reinterpret_cast<const int4*>(gv + base);
      } else {
        const size_t base = (((size_t)b * LL + (kc - 256)) * HH + h) * DD + dg;
        kraw = *reinterpret_cast<const int4*>(lk + base);
        vraw = *reinterpret_cast<const int4*>(lv + base);
      }
      *reinterpret_cast<int4*>(&Kt[key][dg]) = kraw;
      u16 vb[8];
      *reinterpret_cast<int4*>(vb) = vraw;
      #pragma unroll
      for (int j = 0; j < 8; j++) Vt[dg + j][key] = vb[j];
    }
    __syncthreads();

    f32x4 Sacc[4];
    #pragma unroll
    for (int kt = 0; kt < 4; kt++) Sacc[kt] = (f32x4){0.f, 0.f, 0.f, 0.f};
    __builtin_amdgcn_s_setprio(1);
    #pragma unroll
    for (int kk = 0; kk < 2; kk++) {
      bf16x8 bk[4];
      #pragma unroll
      for (int kt = 0; kt < 4; kt++)
        bk[kt] = *reinterpret_cast<const bf16x8*>(&Kt[(kt << 4) + ln][(kk << 5) + (quad << 3)]);
      #pragma unroll
      for (int kt = 0; kt < 4; kt++)
        Sacc[kt] = __builtin_amdgcn_mfma_f32_16x16x32_bf16(aq[kk], bk[kt], Sacc[kt], 0, 0, 0);
    }
    __builtin_amdgcn_s_setprio(0);

    #pragma unroll
    for (int kt = 0; kt < 4; kt++)
      #pragma unroll
      for (int r = 0; r < 4; r++) {
        const int ql = (wv << 4) + (quad << 2) + r;
        float s = fminf(fmaxf(Sacc[kt][r], -60.f), 60.f) + badd[(kt << 2) + r];
        const u16 p16 = f2bf(__expf(s));
        Pt[ql][(kt << 4) + ln] = p16;
        lpart[r] += bf2f(p16);
      }

    __builtin_amdgcn_s_setprio(1);
    #pragma unroll
    for (int kk = 0; kk < 2; kk++) {
      bf16x8 ap = *reinterpret_cast<const bf16x8*>(&Pt[(wv << 4) + ln][(kk << 5) + (quad << 3)]);
      #pragma unroll
      for (int dt = 0; dt < 4; dt++) {
        bf16x8 bv = *reinterpret_cast<const bf16x8*>(&Vt[(dt << 4) + ln][(kk << 5) + (quad << 3)]);
        Oacc[dt] = __builtin_amdgcn_mfma_f32_16x16x32_bf16(ap, bv, Oacc[dt], 0, 0, 0);
      }
    }
    __builtin_amdgcn_s_setprio(0);
  }

  #pragma unroll
  for (int r = 0; r < 4; r++) {
    float v = lpart[r];
    v += __shfl_xor(v, 1); v += __shfl_xor(v, 2);
    v += __shfl_xor(v, 4); v += __shfl_xor(v, 8);
    const int qa = (qt << 6) + (wv << 4) + (quad << 2) + r;
    if (ln == 0)
      pl[(((size_t)chunk * BB + b) * HH + h) * GG + qa] = v;
    const size_t base = ((((size_t)chunk * BB + b) * HH + h) * GG + qa) * DD;
    #pragma unroll
    for (int dt = 0; dt < 4; dt++)
      po[base + (dt << 4) + ln] = Oacc[dt][r];
  }
}

// ---------- combine global-attention partials (17 chunks) ----------
__global__ __launch_bounds__(256)
void gcombine(const float* __restrict__ po, const float* __restrict__ pl,
              u16* __restrict__ gctx) {
  const int flat = blockIdx.x * 256 + threadIdx.x;
  const int d = flat & 63;
  const int rest = flat >> 6;
  const int h = rest % HH;
  const int bq = rest / HH;
  const int b = bq >> 8, qg = bq & 255;
  float so = 0.f, sl = 0.f;
  #pragma unroll
  for (int c = 0; c < NCHUNK; c++) {
    so += po[((((size_t)c * BB + b) * HH + h) * GG + qg) * DD + d];
    sl += pl[(((size_t)c * BB + b) * HH + h) * GG + qg];
  }
  gctx[flat] = f2bf(so / sl);
}

// ---------- host launch ----------
extern "C" void kernel_launch(void* const* d_in, const int* in_sizes, int n_in,
                              void* d_out, int out_size, void* d_ws, size_t ws_size,
                              hipStream_t stream) {
  (void)in_sizes; (void)n_in; (void)out_size; (void)ws_size;
  const void* x_long = d_in[0];
  const void* x_glob = d_in[1];
  const int* m_l2l = (const int*)d_in[2];
  const int* m_g2g = (const int*)d_in[3];
  const int* m_l2g = (const int*)d_in[4];
  const int* m_g2l = (const int*)d_in[5];
  const int* i_l2l = (const int*)d_in[6];
  const int* i_g2g = (const int*)d_in[7];
  const int* i_l2g = (const int*)d_in[8];
  const int* i_g2l = (const int*)d_in[9];
  const void* wq_l = d_in[10]; const void* bq_l = d_in[11];
  const void* wk_l = d_in[12]; const void* bk_l = d_in[13];
  const void* wv_l = d_in[14]; const void* bv_l = d_in[15];
  const void* wq_g = d_in[16]; const void* bq_g = d_in[17];
  const void* wk_g = d_in[18]; const void* bk_g = d_in[19];
  const void* wv_g = d_in[20]; const void* bv_g = d_in[21];
  const void* rel_emb_l = d_in[22]; const void* rel_bias_l = d_in[23];
  const void* rel_emb_g = d_in[24]; const void* rel_bias_g = d_in[25];
  const void* wo_l = d_in[26]; const void* bo_l = d_in[27];
  const void* wo_g = d_in[28]; const void* bo_g = d_in[29];

  constexpr size_t NLQ = (size_t)BB * LL * HH * DD;
  constexpr size_t NG  = (size_t)BB * GG * HH * DD;
  constexpr size_t NRL = (size_t)BB * LL * HH * VV;
  constexpr size_t NRG = (size_t)BB * GG * HH * VV;
  u16* lqw  = reinterpret_cast<u16*>(d_ws);
  u16* lkw  = lqw + NLQ;
  u16* lvw  = lkw + NLQ;
  u16* gqw  = lvw + NLQ;
  u16* gkw  = gqw + NG;
  u16* gvw  = gkw + NG;
  u16* rell = gvw + NG;
  u16* relg = rell + NRL;
  u16* lctx = relg + NRG;
  u16* gctx = lctx + NLQ;
  int* flag = reinterpret_cast<int*>(gctx + NG);
  float* po = reinterpret_cast<float*>(flag + 16);          // [17][B][H][G][D]
  float* pl = po + (size_t)NCHUNK * BB * HH * GG * DD;      // [17][B][H][G]
  // pk_l OVERLAYS po: pack_l writes it at stream start; lattn (its only
  // reader) completes before gattn starts writing po (same-stream order).
  // Keeps workspace high-water within ~2.2 MB of the previous proven layout.
  u8* pk_l = reinterpret_cast<u8*>(po);                     // [B][L][640]
  u8* pk_g = reinterpret_cast<u8*>(pl + (size_t)NCHUNK * BB * HH * GG);  // [B][G][4352]

  dim3 t256(256);
  detect_dtype<<<1, t256, 0, stream>>>(x_long, flag);
  pack_l<<<dim3((BB * LL * LKEY) / 256), t256, 0, stream>>>(m_l2l, m_l2g, i_l2l, i_l2g, pk_l);
  pack_g<<<dim3((BB * GG * GKEY) / 256), t256, 0, stream>>>(m_g2g, m_g2l, i_g2g, i_g2l, pk_g);
  gemm_qkv<<<dim3(36, 64), t256, 0, stream>>>(x_long, wq_l, wk_l, wv_l,
                                              bq_l, bk_l, bv_l, lqw, lkw, lvw,
                                              BB * LL, flag);
  gemm_qkv<<<dim3(36, 4), t256, 0, stream>>>(x_glob, wq_g, wk_g, wv_g,
                                             bq_g, bk_g, bv_g, gqw, gkw, gvw,
                                             BB * GG, flag);
  relk<<<dim3(64, 12, 2), t256, 0, stream>>>(lqw, rel_emb_l, rel_bias_l, rell, LL, flag);
  relk<<<dim3(4, 12, 2), t256, 0, stream>>>(gqw, rel_emb_g, rel_bias_g, relg, GG, flag);
  lattn<<<dim3(12, 32, 2), dim3(512), 0, stream>>>(lqw, lkw, lvw, gkw, gvw,
                                                   pk_l, rell, lctx);
  gattn<<<dim3(12, NCHUNK, 8), t256, 0, stream>>>(gqw, gkw, gvw, lkw, lvw,
                                                  pk_g, relg, po, pl);
  gcombine<<<dim3(1536), t256, 0, stream>>>(po, pl, gctx);
  gemm_out<<<dim3(12, 64), t256, 0, stream>>>(lctx, wo_l, bo_l, d_out, 0, BB * LL, flag);
  gemm_out<<<dim3(12, 4), t256, 0, stream>>>(gctx, wo_g, bo_g, d_out, (size_t)BB * LL * 768, BB * GG, flag);
}